// Round 5
// baseline (500.948 us; speedup 1.0000x reference)
//
#include <hip/hip_runtime.h>

// PhaMPN v5: bf16-message + MFMA pipeline.
//   binput = fedges @ W_i (MFMA, stored bf16); msg = bf16(sigmoid(binput))
//   5x: msg = bf16(sigmoid(binput + (sum_8 msg[egraph]) @ W_h))   [MFMA bf16]
//   nei = sum_8 msg[agraph]; hidden = bf16(sigmoid([feat|nei] @ W_o + b_o)) [MFMA]
//   out = segment-mean(hidden) per scope row (B=500, len=100), f32
// v5: k_iter gathers neighbor sums DIRECTLY into MFMA A-fragments (no LDS
//     round-trip); all weights stored fragment-major so B-reads are lane-linear
//     ds_read_b128 (zero bank conflicts); acc staging halved -> 37.4 KB LDS.

typedef __attribute__((ext_vector_type(4))) float f32x4;
typedef __attribute__((ext_vector_type(8))) short s16x8;
typedef unsigned short u16;

constexpr int Nn   = 50000;
constexpr int Ee   = 150000;
constexpr int NBn  = 8;
constexpr int Hh   = 128;
constexpr int FFn  = 40;
constexpr int Bm   = 500;
constexpr int ITERS = 5;       // DEPTH - 1
constexpr int KI   = 72;       // fedges-tile stride (K padded 41->64)
constexpr int KO   = 200;      // k_final A-tile stride (K padded 168->192)
constexpr int ACCW = 132;      // f32 acc stride (k_binput / k_final)
constexpr int ACC2 = 130;      // f32 acc stride (k_iter halves)

__device__ __forceinline__ float sigmoidf_(float x) {
    return 1.0f / (1.0f + __expf(-x));
}
// f32 -> bf16 round-to-nearest-even (finite values only)
__device__ __forceinline__ u16 f2bf(float f) {
    unsigned u = __float_as_uint(f);
    u += 0x7fffu + ((u >> 16) & 1u);
    return (u16)(u >> 16);
}
__device__ __forceinline__ float bflo(unsigned u) { return __uint_as_float(u << 16); }
__device__ __forceinline__ float bfhi(unsigned u) { return __uint_as_float(u & 0xffff0000u); }
__device__ __forceinline__ float bf1(u16 h) { return __uint_as_float(((unsigned)h) << 16); }
__device__ __forceinline__ unsigned pack2(float x, float y) {
    return (unsigned)f2bf(x) | ((unsigned)f2bf(y) << 16);
}
__device__ __forceinline__ void add8(float* a, uint4 v) {
    a[0] += bflo(v.x); a[1] += bfhi(v.x); a[2] += bflo(v.y); a[3] += bfhi(v.y);
    a[4] += bflo(v.z); a[5] += bfhi(v.z); a[6] += bflo(v.w); a[7] += bfhi(v.w);
}

// ---------------------------------------------------------------------------
// Fragment-major weight layout: flat index i -> frag f = i>>9, lane l = (i>>3)&63,
// elem e = i&7;  ks = f>>3, c = f&7;  k = ks*32 + (l>>4)*8 + e;  n = c*16 + (l&15).
// MFMA B-read is then ((s16x8*)W)[f*64 + lane]  (lane-linear, conflict-free).
// ---------------------------------------------------------------------------
__global__ __launch_bounds__(256) void k_prep1(
    const float* __restrict__ W_h, const float* __restrict__ W_i,
    u16* __restrict__ wt_h, u16* __restrict__ wt_i)
{
    int i = blockIdx.x * 256 + threadIdx.x;
    if (i < Hh * Hh) {                       // wt_h: 32 frags (ks 0..3)
        int f = i >> 9, l = (i >> 3) & 63, e = i & 7;
        int ks = f >> 3, c = f & 7;
        int k = ks * 32 + (l >> 4) * 8 + e, n = c * 16 + (l & 15);
        wt_h[i] = f2bf(W_h[k * Hh + n]);
    } else {
        int j = i - Hh * Hh;
        if (j < 16 * 512) {                  // wt_i: 16 frags (ks 0..1), k<41 else 0
            int f = j >> 9, l = (j >> 3) & 63, e = j & 7;
            int ks = f >> 3, c = f & 7;
            int k = ks * 32 + (l >> 4) * 8 + e, n = c * 16 + (l & 15);
            wt_i[j] = (k < 41) ? f2bf(W_i[k * Hh + n]) : (u16)0;
        }
    }
}

__global__ __launch_bounds__(256) void k_prep2(
    const float* __restrict__ W_o, u16* __restrict__ wt_o)
{
    int i = blockIdx.x * 256 + threadIdx.x;
    if (i < 48 * 512) {                      // wt_o: 48 frags (ks 0..5)
        int f = i >> 9, l = (i >> 3) & 63, e = i & 7;
        int ks = f >> 3, c = f & 7;
        int k = ks * 32 + (l >> 4) * 8 + e, n = c * 16 + (l & 15);
        u16 v = 0;
        if (k < FFn)                 v = f2bf(W_o[k * Hh + n]);
        else if (k >= 64 && k < 192) v = f2bf(W_o[(k - 24) * Hh + n]);
        wt_o[i] = v;
    }
}

// ---------------------------------------------------------------------------
// Kernel 1 (MFMA, 512 thr): binput_bf = bf16(fedges @ W_i); msg = bf16(sigmoid)
// 128 rows / block, 8 waves, K=64 (padded).
// ---------------------------------------------------------------------------
union BinSmem {
    struct { u16 Wi[16 * 512]; u16 A[Hh * KI]; } s;  // 16384 + 18432 B
    float acc[Hh][ACCW];                             // 67584 B
};

__global__ __launch_bounds__(512, 4) void k_binput(
    const float* __restrict__ fedges, const u16* __restrict__ wt_i,
    u16* __restrict__ binput_bf, u16* __restrict__ msg)
{
    __shared__ BinSmem u;
    const int t = threadIdx.x;
    const int row0 = blockIdx.x * 128;
    const int nvalid = min(128, Ee - row0);

    {
        uint4 z = make_uint4(0, 0, 0, 0);
        for (int i = t; i < Hh * KI / 8; i += 512) {
            if (i < 1024) ((uint4*)u.s.Wi)[i] = ((const uint4*)wt_i)[i];
            ((uint4*)u.s.A)[i] = z;
        }
    }
    __syncthreads();
    for (int i = t; i < nvalid * 41; i += 512) {
        int r = i / 41, k = i - r * 41;
        u.s.A[r * KI + k] = f2bf(fedges[(size_t)row0 * 41 + i]);
    }
    __syncthreads();

    const int lane = t & 63, wid = t >> 6, l15 = lane & 15, l4 = lane >> 4;
    f32x4 acc[8];
    #pragma unroll
    for (int b = 0; b < 8; ++b) acc[b] = (f32x4){0.f, 0.f, 0.f, 0.f};

    #pragma unroll
    for (int ks = 0; ks < 2; ++ks) {
        s16x8 a = *(const s16x8*)&u.s.A[(wid * 16 + l15) * KI + ks * 32 + l4 * 8];
        #pragma unroll
        for (int c = 0; c < 8; ++c) {
            s16x8 b = ((const s16x8*)u.s.Wi)[(ks * 8 + c) * 64 + lane];
            acc[c] = __builtin_amdgcn_mfma_f32_16x16x32_bf16(a, b, acc[c], 0, 0, 0);
        }
    }
    __syncthreads();

    #pragma unroll
    for (int c = 0; c < 8; ++c)
        #pragma unroll
        for (int j = 0; j < 4; ++j)
            u.acc[wid * 16 + l4 * 4 + j][c * 16 + l15] = acc[c][j];
    __syncthreads();

    for (int i = t; i < Hh * 16; i += 512) {
        int row = i >> 4, seg = i & 15, grow = row0 + row;
        if (grow < Ee) {
            float4 a0 = *(const float4*)&u.acc[row][seg * 8];
            float4 a1 = *(const float4*)&u.acc[row][seg * 8 + 4];
            size_t o = (size_t)grow * Hh + seg * 8;
            uint4 bv;
            bv.x = pack2(a0.x, a0.y); bv.y = pack2(a0.z, a0.w);
            bv.z = pack2(a1.x, a1.y); bv.w = pack2(a1.z, a1.w);
            *(uint4*)&binput_bf[o] = bv;
            uint4 m;
            m.x = pack2(sigmoidf_(a0.x), sigmoidf_(a0.y));
            m.y = pack2(sigmoidf_(a0.z), sigmoidf_(a0.w));
            m.z = pack2(sigmoidf_(a1.x), sigmoidf_(a1.y));
            m.w = pack2(sigmoidf_(a1.z), sigmoidf_(a1.w));
            *(uint4*)&msg[o] = m;
        }
    }
}

// ---------------------------------------------------------------------------
// Kernel 2 (MFMA, 512 thr): msg_out = bf16(sigmoid(binput + (sum_8 msg)@W_h))
// 128 rows / block, 8 waves. Gather -> A-fragments in registers (no LDS trip).
// LDS: union(Wfrag 32KB | acc64 33.3KB) + sEG 4KB = 37.4 KB -> up to 4 blk/CU.
// ---------------------------------------------------------------------------
union IterSmem {
    u16 W[Hh * Hh];             // 32768 B, fragment-major
    float acc[64][ACC2];        // 33280 B
};

__global__ __launch_bounds__(512, 4) void k_iter(
    const u16* __restrict__ msg_in, const int* __restrict__ egraph,
    const u16* __restrict__ wt_h, const u16* __restrict__ binput_bf,
    u16* __restrict__ msg_out)
{
    __shared__ IterSmem u;
    __shared__ int sEG[128 * NBn];
    const int t = threadIdx.x;
    const int row0 = blockIdx.x * 128;
    const int lane = t & 63, wid = t >> 6, l15 = lane & 15, l4 = lane >> 4;

    // stage fragment-major W (linear) and edge indices
    for (int i = t; i < Hh * Hh / 8; i += 512)
        ((uint4*)u.W)[i] = ((const uint4*)wt_h)[i];
    if (t < 256) {
        int r = row0 + (t >> 1);
        int4 v = make_int4(0, 0, 0, 0);
        if (r < Ee) v = ((const int4*)egraph)[r * 2 + (t & 1)];
        ((int4*)sEG)[t] = v;
    }
    __syncthreads();

    // ---- gather neighbor sums directly into A fragments ----
    const int arow = wid * 16 + l15;      // local edge row this lane fragments
    int4 q0 = ((const int4*)&sEG[arow * NBn])[0];
    int4 q1 = ((const int4*)&sEG[arow * NBn])[1];
    int idx[8] = {q0.x, q0.y, q0.z, q0.w, q1.x, q1.y, q1.z, q1.w};

    s16x8 afrag[4];
    #pragma unroll
    for (int half = 0; half < 2; ++half) {
        float a0[8] = {0.f, 0.f, 0.f, 0.f, 0.f, 0.f, 0.f, 0.f};
        float a1[8] = {0.f, 0.f, 0.f, 0.f, 0.f, 0.f, 0.f, 0.f};
        #pragma unroll
        for (int j = 0; j < NBn; ++j) {
            const u16* p = msg_in + (size_t)idx[j] * Hh + half * 64 + l4 * 8;
            uint4 v0 = *(const uint4*)p;          // dims half*64 + l4*8 ..+8
            uint4 v1 = *(const uint4*)(p + 32);   // dims half*64 + 32 + l4*8 ..+8
            add8(a0, v0);
            add8(a1, v1);
        }
        s16x8 f0, f1;
        #pragma unroll
        for (int e = 0; e < 8; ++e) {
            f0[e] = (short)f2bf(a0[e]);
            f1[e] = (short)f2bf(a1[e]);
        }
        afrag[2 * half]     = f0;
        afrag[2 * half + 1] = f1;
    }

    // ---- MFMA: B-reads are lane-linear (conflict-free) ----
    f32x4 acc[8];
    #pragma unroll
    for (int b = 0; b < 8; ++b) acc[b] = (f32x4){0.f, 0.f, 0.f, 0.f};
    #pragma unroll
    for (int ks = 0; ks < 4; ++ks)
        #pragma unroll
        for (int c = 0; c < 8; ++c) {
            s16x8 b = ((const s16x8*)u.W)[(ks * 8 + c) * 64 + lane];
            acc[c] = __builtin_amdgcn_mfma_f32_16x16x32_bf16(afrag[ks], b, acc[c], 0, 0, 0);
        }
    __syncthreads();   // all waves done reading W -> union region reusable

    // ---- epilogue in two 64-row halves through the union acc buffer ----
    #pragma unroll
    for (int h = 0; h < 2; ++h) {
        if ((wid >> 2) == h) {
            #pragma unroll
            for (int c = 0; c < 8; ++c)
                #pragma unroll
                for (int j = 0; j < 4; ++j)
                    u.acc[(wid & 3) * 16 + l4 * 4 + j][c * 16 + l15] = acc[c][j];
        }
        __syncthreads();
        for (int i = t; i < 64 * 16; i += 512) {
            int r = i >> 4, seg = i & 15;
            int g = row0 + h * 64 + r;
            if (g < Ee) {
                float4 a0 = *(const float4*)&u.acc[r][seg * 8];
                float4 a1 = *(const float4*)&u.acc[r][seg * 8 + 4];
                size_t o = (size_t)g * Hh + seg * 8;
                uint4 bv = *(const uint4*)&binput_bf[o];
                uint4 m;
                m.x = pack2(sigmoidf_(a0.x + bflo(bv.x)), sigmoidf_(a0.y + bfhi(bv.x)));
                m.y = pack2(sigmoidf_(a0.z + bflo(bv.y)), sigmoidf_(a0.w + bfhi(bv.y)));
                m.z = pack2(sigmoidf_(a1.x + bflo(bv.z)), sigmoidf_(a1.y + bfhi(bv.z)));
                m.w = pack2(sigmoidf_(a1.z + bflo(bv.w)), sigmoidf_(a1.w + bfhi(bv.w)));
                *(uint4*)&msg_out[o] = m;
            }
        }
        __syncthreads();
    }
}

// ---------------------------------------------------------------------------
// Kernel 3 (MFMA): hidden = bf16(sigmoid([feat|0pad|nei] @ W_o' + b_o)), K=192
// 64 rows / block, 4 waves. Fragment-major W_o.
// ---------------------------------------------------------------------------
union WoSmem {
    u16 Wo[48 * 512];       // 49152 B, fragment-major
    float acc[64][ACCW];    // 33792 B
};

__global__ __launch_bounds__(256, 2) void k_final(
    const u16* __restrict__ msg_in, const int* __restrict__ agraph,
    const float* __restrict__ features, const u16* __restrict__ wt_o,
    const float* __restrict__ b_o, u16* __restrict__ hidden)
{
    __shared__ WoSmem uw;
    __shared__ u16 sA[64 * KO];     // 25600 B
    __shared__ int sAG[64 * NBn];   // 2048 B
    __shared__ float sBias[Hh];     // 512 B
    const int t = threadIdx.x;
    const int row0 = blockIdx.x * 64;
    const int nvalid = min(64, Nn - row0);

    for (int i = t; i < 48 * 512 / 8; i += 256)
        ((uint4*)uw.Wo)[i] = ((const uint4*)wt_o)[i];
    {
        uint4 z = make_uint4(0, 0, 0, 0);
        for (int i = t; i < 64 * KO / 8; i += 256) ((uint4*)sA)[i] = z;
    }
    if (t < 128) {
        int r = row0 + (t >> 1);
        int4 v = make_int4(0, 0, 0, 0);
        if (r < Nn) v = ((const int4*)agraph)[r * 2 + (t & 1)];
        ((int4*)sAG)[t] = v;
    }
    if (t < Hh / 4) ((float4*)sBias)[t] = ((const float4*)b_o)[t];
    __syncthreads();

    for (int i = t; i < nvalid * FFn; i += 256) {
        int r = i / FFn, k = i - r * FFn;
        sA[r * KO + k] = f2bf(features[(size_t)row0 * FFn + i]);
    }
    {
        const int s = t & 15, rl = t >> 4;
        #pragma unroll 2
        for (int pass = 0; pass < 4; ++pass) {
            int r = pass * 16 + rl;
            int grow = row0 + r;
            float a[8] = {0.f, 0.f, 0.f, 0.f, 0.f, 0.f, 0.f, 0.f};
            if (grow < Nn) {
                #pragma unroll
                for (int j = 0; j < NBn; ++j) {
                    int idx = sAG[r * NBn + j];
                    uint4 v = *(const uint4*)(msg_in + (size_t)idx * Hh + s * 8);
                    add8(a, v);
                }
            }
            uint4 o;
            o.x = pack2(a[0], a[1]); o.y = pack2(a[2], a[3]);
            o.z = pack2(a[4], a[5]); o.w = pack2(a[6], a[7]);
            *(uint4*)&sA[r * KO + 64 + s * 8] = o;
        }
    }
    __syncthreads();

    const int lane = t & 63, wid = t >> 6, l15 = lane & 15, l4 = lane >> 4;
    f32x4 acc[8];
    #pragma unroll
    for (int b = 0; b < 8; ++b) acc[b] = (f32x4){0.f, 0.f, 0.f, 0.f};

    #pragma unroll
    for (int ks = 0; ks < 6; ++ks) {
        s16x8 a = *(const s16x8*)&sA[(wid * 16 + l15) * KO + ks * 32 + l4 * 8];
        #pragma unroll
        for (int c = 0; c < 8; ++c) {
            s16x8 b = ((const s16x8*)uw.Wo)[(ks * 8 + c) * 64 + lane];
            acc[c] = __builtin_amdgcn_mfma_f32_16x16x32_bf16(a, b, acc[c], 0, 0, 0);
        }
    }
    __syncthreads();

    #pragma unroll
    for (int c = 0; c < 8; ++c)
        #pragma unroll
        for (int j = 0; j < 4; ++j)
            uw.acc[wid * 16 + l4 * 4 + j][c * 16 + l15] = acc[c][j];
    __syncthreads();

    for (int i = t; i < 64 * 16; i += 256) {
        int row = i >> 4, seg = i & 15, grow = row0 + row;
        if (grow < Nn) {
            float4 a0 = *(const float4*)&uw.acc[row][seg * 8];
            float4 a1 = *(const float4*)&uw.acc[row][seg * 8 + 4];
            const float* bb = &sBias[seg * 8];
            uint4 m;
            m.x = pack2(sigmoidf_(a0.x + bb[0]), sigmoidf_(a0.y + bb[1]));
            m.y = pack2(sigmoidf_(a0.z + bb[2]), sigmoidf_(a0.w + bb[3]));
            m.z = pack2(sigmoidf_(a1.x + bb[4]), sigmoidf_(a1.y + bb[5]));
            m.w = pack2(sigmoidf_(a1.z + bb[6]), sigmoidf_(a1.w + bb[7]));
            *(uint4*)&hidden[(size_t)grow * Hh + seg * 8] = m;
        }
    }
}

// ---------------------------------------------------------------------------
// Kernel 4: segment mean over bf16 hidden. One block (128 threads) / molecule.
// ---------------------------------------------------------------------------
__global__ __launch_bounds__(128) void k_pool(
    const u16* __restrict__ hidden, const int* __restrict__ scope,
    float* __restrict__ out)
{
    const int b = blockIdx.x;
    const int t = threadIdx.x;
    const int start = scope[b * 2 + 0];
    const int len   = scope[b * 2 + 1];
    float acc = 0.f;
    for (int i = 0; i < len; ++i)
        acc += bf1(hidden[(size_t)(start + i) * Hh + t]);
    out[(size_t)b * Hh + t] = acc / (float)len;
}

// ---------------------------------------------------------------------------
extern "C" void kernel_launch(void* const* d_in, const int* in_sizes, int n_in,
                              void* d_out, int out_size, void* d_ws, size_t ws_size,
                              hipStream_t stream)
{
    const float* features = (const float*)d_in[0];
    const float* fedges   = (const float*)d_in[1];
    const int*   agraph   = (const int*)d_in[2];
    const int*   egraph   = (const int*)d_in[3];
    const int*   scope    = (const int*)d_in[4];
    const float* W_i      = (const float*)d_in[5];
    const float* W_h      = (const float*)d_in[6];
    const float* W_o      = (const float*)d_in[7];
    const float* b_o      = (const float*)d_in[8];
    float* out = (float*)d_out;

    // Workspace: binput bf16[E*128] | msg0 bf16[E*128] | msg1 bf16[E*128] | wt_h
    // wt_i parks in msg1 (consumed by k_binput before iter0 writes msg1);
    // wt_o parks in binput region (prepped after the last k_iter).
    u16* binput_bf = (u16*)d_ws;
    u16* msg0 = binput_bf + (size_t)Ee * Hh;
    u16* msg1 = msg0 + (size_t)Ee * Hh;
    u16* wt_h = msg1 + (size_t)Ee * Hh;      // 16384 u16
    u16* wt_i = msg1;                        // 8192 u16
    u16* wt_o = binput_bf;                   // 24576 u16

    k_prep1<<<(Hh * Hh + 16 * 512 + 255) / 256, 256, 0, stream>>>(W_h, W_i, wt_h, wt_i);

    const int eblocks = (Ee + 127) / 128;
    k_binput<<<eblocks, 512, 0, stream>>>(fedges, wt_i, binput_bf, msg0);

    u16* src = msg0;
    u16* dst = msg1;
    for (int d = 0; d < ITERS; ++d) {
        k_iter<<<eblocks, 512, 0, stream>>>(src, egraph, wt_h, binput_bf, dst);
        u16* tmp = src; src = dst; dst = tmp;
    }
    // final message in `src` (= msg1); binput now dead -> prep wt_o there.
    k_prep2<<<(48 * 512) / 256, 256, 0, stream>>>(W_o, wt_o);

    u16* hidden = dst;   // = msg0 region
    const int nblocks = (Nn + 63) / 64;
    k_final<<<nblocks, 256, 0, stream>>>(src, agraph, features, wt_o, b_o, hidden);

    k_pool<<<Bm, 128, 0, stream>>>(hidden, scope, out);
}

// Round 6
// 500.082 us; speedup vs baseline: 1.0017x; 1.0017x over previous
//
#include <hip/hip_runtime.h>

// PhaMPN v6: bf16-message + MFMA pipeline, gather/GEMM split.
//   binput = fedges @ W_i (MFMA, stored bf16); msg = bf16(sigmoid(binput))
//   5x: nei = sum_8 msg[egraph]        [k_gather: pure latency-optimized gather]
//       msg = bf16(sigmoid(binput + nei @ W_h))   [k_gemm: streaming MFMA]
//   nei = sum_8 msg[agraph]; hidden = bf16(sigmoid([feat|nei] @ W_o + b_o))
//   out = segment-mean(hidden) per scope row (B=500, len=100), f32

typedef __attribute__((ext_vector_type(4))) float f32x4;
typedef __attribute__((ext_vector_type(8))) short s16x8;
typedef unsigned short u16;

constexpr int Nn   = 50000;
constexpr int Ee   = 150000;
constexpr int NBn  = 8;
constexpr int Hh   = 128;
constexpr int FFn  = 40;
constexpr int Bm   = 500;
constexpr int ITERS = 5;       // DEPTH - 1
constexpr int KI   = 72;       // fedges-tile stride (K padded 41->64)
constexpr int KO   = 200;      // k_final A-tile stride (K padded 168->192)
constexpr int ACCW = 132;      // f32 acc stride (k_binput / k_final)
constexpr int ACC2 = 130;      // f32 acc stride (k_gemm halves)

__device__ __forceinline__ float sigmoidf_(float x) {
    return 1.0f / (1.0f + __expf(-x));
}
// f32 -> bf16 round-to-nearest-even (finite values only)
__device__ __forceinline__ u16 f2bf(float f) {
    unsigned u = __float_as_uint(f);
    u += 0x7fffu + ((u >> 16) & 1u);
    return (u16)(u >> 16);
}
__device__ __forceinline__ float bflo(unsigned u) { return __uint_as_float(u << 16); }
__device__ __forceinline__ float bfhi(unsigned u) { return __uint_as_float(u & 0xffff0000u); }
__device__ __forceinline__ float bf1(u16 h) { return __uint_as_float(((unsigned)h) << 16); }
__device__ __forceinline__ unsigned pack2(float x, float y) {
    return (unsigned)f2bf(x) | ((unsigned)f2bf(y) << 16);
}
__device__ __forceinline__ void add8(float* a, uint4 v) {
    a[0] += bflo(v.x); a[1] += bfhi(v.x); a[2] += bflo(v.y); a[3] += bfhi(v.y);
    a[4] += bflo(v.z); a[5] += bfhi(v.z); a[6] += bflo(v.w); a[7] += bfhi(v.w);
}

// ---------------------------------------------------------------------------
// Fragment-major weight layout: flat index i -> frag f = i>>9, lane l = (i>>3)&63,
// elem e = i&7;  ks = f>>3, c = f&7;  k = ks*32 + (l>>4)*8 + e;  n = c*16 + (l&15).
// MFMA B-read is then ((s16x8*)W)[f*64 + lane]  (lane-linear, conflict-free).
// ---------------------------------------------------------------------------
__global__ __launch_bounds__(256) void k_prep1(
    const float* __restrict__ W_h, const float* __restrict__ W_i,
    u16* __restrict__ wt_h, u16* __restrict__ wt_i)
{
    int i = blockIdx.x * 256 + threadIdx.x;
    if (i < Hh * Hh) {                       // wt_h: 32 frags (ks 0..3)
        int f = i >> 9, l = (i >> 3) & 63, e = i & 7;
        int ks = f >> 3, c = f & 7;
        int k = ks * 32 + (l >> 4) * 8 + e, n = c * 16 + (l & 15);
        wt_h[i] = f2bf(W_h[k * Hh + n]);
    } else {
        int j = i - Hh * Hh;
        if (j < 16 * 512) {                  // wt_i: 16 frags (ks 0..1), k<41 else 0
            int f = j >> 9, l = (j >> 3) & 63, e = j & 7;
            int ks = f >> 3, c = f & 7;
            int k = ks * 32 + (l >> 4) * 8 + e, n = c * 16 + (l & 15);
            wt_i[j] = (k < 41) ? f2bf(W_i[k * Hh + n]) : (u16)0;
        }
    }
}

__global__ __launch_bounds__(256) void k_prep2(
    const float* __restrict__ W_o, u16* __restrict__ wt_o)
{
    int i = blockIdx.x * 256 + threadIdx.x;
    if (i < 48 * 512) {                      // wt_o: 48 frags (ks 0..5)
        int f = i >> 9, l = (i >> 3) & 63, e = i & 7;
        int ks = f >> 3, c = f & 7;
        int k = ks * 32 + (l >> 4) * 8 + e, n = c * 16 + (l & 15);
        u16 v = 0;
        if (k < FFn)                 v = f2bf(W_o[k * Hh + n]);
        else if (k >= 64 && k < 192) v = f2bf(W_o[(k - 24) * Hh + n]);
        wt_o[i] = v;
    }
}

// ---------------------------------------------------------------------------
// Kernel 1 (MFMA, 512 thr): binput_bf = bf16(fedges @ W_i); msg = bf16(sigmoid)
// 128 rows / block, 8 waves, K=64 (padded).
// ---------------------------------------------------------------------------
union BinSmem {
    struct { u16 Wi[16 * 512]; u16 A[Hh * KI]; } s;  // 16384 + 18432 B
    float acc[Hh][ACCW];                             // 67584 B
};

__global__ __launch_bounds__(512, 4) void k_binput(
    const float* __restrict__ fedges, const u16* __restrict__ wt_i,
    u16* __restrict__ binput_bf, u16* __restrict__ msg)
{
    __shared__ BinSmem u;
    const int t = threadIdx.x;
    const int row0 = blockIdx.x * 128;
    const int nvalid = min(128, Ee - row0);

    {
        uint4 z = make_uint4(0, 0, 0, 0);
        for (int i = t; i < Hh * KI / 8; i += 512) {
            if (i < 1024) ((uint4*)u.s.Wi)[i] = ((const uint4*)wt_i)[i];
            ((uint4*)u.s.A)[i] = z;
        }
    }
    __syncthreads();
    for (int i = t; i < nvalid * 41; i += 512) {
        int r = i / 41, k = i - r * 41;
        u.s.A[r * KI + k] = f2bf(fedges[(size_t)row0 * 41 + i]);
    }
    __syncthreads();

    const int lane = t & 63, wid = t >> 6, l15 = lane & 15, l4 = lane >> 4;
    f32x4 acc[8];
    #pragma unroll
    for (int b = 0; b < 8; ++b) acc[b] = (f32x4){0.f, 0.f, 0.f, 0.f};

    #pragma unroll
    for (int ks = 0; ks < 2; ++ks) {
        s16x8 a = *(const s16x8*)&u.s.A[(wid * 16 + l15) * KI + ks * 32 + l4 * 8];
        #pragma unroll
        for (int c = 0; c < 8; ++c) {
            s16x8 b = ((const s16x8*)u.s.Wi)[(ks * 8 + c) * 64 + lane];
            acc[c] = __builtin_amdgcn_mfma_f32_16x16x32_bf16(a, b, acc[c], 0, 0, 0);
        }
    }
    __syncthreads();

    #pragma unroll
    for (int c = 0; c < 8; ++c)
        #pragma unroll
        for (int j = 0; j < 4; ++j)
            u.acc[wid * 16 + l4 * 4 + j][c * 16 + l15] = acc[c][j];
    __syncthreads();

    for (int i = t; i < Hh * 16; i += 512) {
        int row = i >> 4, seg = i & 15, grow = row0 + row;
        if (grow < Ee) {
            float4 a0 = *(const float4*)&u.acc[row][seg * 8];
            float4 a1 = *(const float4*)&u.acc[row][seg * 8 + 4];
            size_t o = (size_t)grow * Hh + seg * 8;
            uint4 bv;
            bv.x = pack2(a0.x, a0.y); bv.y = pack2(a0.z, a0.w);
            bv.z = pack2(a1.x, a1.y); bv.w = pack2(a1.z, a1.w);
            *(uint4*)&binput_bf[o] = bv;
            uint4 m;
            m.x = pack2(sigmoidf_(a0.x), sigmoidf_(a0.y));
            m.y = pack2(sigmoidf_(a0.z), sigmoidf_(a0.w));
            m.z = pack2(sigmoidf_(a1.x), sigmoidf_(a1.y));
            m.w = pack2(sigmoidf_(a1.z), sigmoidf_(a1.w));
            *(uint4*)&msg[o] = m;
        }
    }
}

// ---------------------------------------------------------------------------
// Kernel 2a: nei[row] = bf16(sum_8 msg_in[egraph[row]]).  Pure gather.
// 8 lanes/row x 32B; all 16 dwordx4 loads per lane issued before consumption
// (max memory-level parallelism); no LDS, no barriers -> high occupancy.
// ---------------------------------------------------------------------------
__global__ __launch_bounds__(256, 4) void k_gather(
    const u16* __restrict__ msg_in, const int* __restrict__ egraph,
    u16* __restrict__ nei)
{
    const int gid = blockIdx.x * 256 + threadIdx.x;
    const int row = gid >> 3;
    const int s   = gid & 7;
    if (row >= Ee) return;

    const int4 q0 = ((const int4*)egraph)[row * 2];
    const int4 q1 = ((const int4*)egraph)[row * 2 + 1];
    const u16* base = msg_in + (size_t)s * 16;

    const u16* p0 = base + (size_t)q0.x * Hh;
    const u16* p1 = base + (size_t)q0.y * Hh;
    const u16* p2 = base + (size_t)q0.z * Hh;
    const u16* p3 = base + (size_t)q0.w * Hh;
    const u16* p4 = base + (size_t)q1.x * Hh;
    const u16* p5 = base + (size_t)q1.y * Hh;
    const u16* p6 = base + (size_t)q1.z * Hh;
    const u16* p7 = base + (size_t)q1.w * Hh;

    uint4 v0a = *(const uint4*)p0, v0b = *(const uint4*)(p0 + 8);
    uint4 v1a = *(const uint4*)p1, v1b = *(const uint4*)(p1 + 8);
    uint4 v2a = *(const uint4*)p2, v2b = *(const uint4*)(p2 + 8);
    uint4 v3a = *(const uint4*)p3, v3b = *(const uint4*)(p3 + 8);
    uint4 v4a = *(const uint4*)p4, v4b = *(const uint4*)(p4 + 8);
    uint4 v5a = *(const uint4*)p5, v5b = *(const uint4*)(p5 + 8);
    uint4 v6a = *(const uint4*)p6, v6b = *(const uint4*)(p6 + 8);
    uint4 v7a = *(const uint4*)p7, v7b = *(const uint4*)(p7 + 8);

    float a[16];
    #pragma unroll
    for (int i = 0; i < 16; ++i) a[i] = 0.f;
    add8(a, v0a); add8(a + 8, v0b);
    add8(a, v1a); add8(a + 8, v1b);
    add8(a, v2a); add8(a + 8, v2b);
    add8(a, v3a); add8(a + 8, v3b);
    add8(a, v4a); add8(a + 8, v4b);
    add8(a, v5a); add8(a + 8, v5b);
    add8(a, v6a); add8(a + 8, v6b);
    add8(a, v7a); add8(a + 8, v7b);

    uint4 o0, o1;
    o0.x = pack2(a[0],  a[1]);  o0.y = pack2(a[2],  a[3]);
    o0.z = pack2(a[4],  a[5]);  o0.w = pack2(a[6],  a[7]);
    o1.x = pack2(a[8],  a[9]);  o1.y = pack2(a[10], a[11]);
    o1.z = pack2(a[12], a[13]); o1.w = pack2(a[14], a[15]);
    u16* q = nei + (size_t)row * Hh + (size_t)s * 16;
    *(uint4*)q       = o0;
    *(uint4*)(q + 8) = o1;
}

// ---------------------------------------------------------------------------
// Kernel 2b (MFMA, 512 thr): msg_out = bf16(sigmoid(binput + nei @ W_h))
// 128 rows / block. A-frags streamed directly from nei (bf16); frag-major W.
// LDS: union(Wfrag 32KB | acc64 33.3KB) = 33.3KB.
// ---------------------------------------------------------------------------
union GemmSmem {
    u16 W[Hh * Hh];             // 32768 B, fragment-major
    float acc[64][ACC2];        // 33280 B
};

__global__ __launch_bounds__(512, 4) void k_gemm(
    const u16* __restrict__ nei, const u16* __restrict__ wt_h,
    const u16* __restrict__ binput_bf, u16* __restrict__ msg_out)
{
    __shared__ GemmSmem u;
    const int t = threadIdx.x;
    const int row0 = blockIdx.x * 128;
    const int lane = t & 63, wid = t >> 6, l15 = lane & 15, l4 = lane >> 4;

    for (int i = t; i < Hh * Hh / 8; i += 512)
        ((uint4*)u.W)[i] = ((const uint4*)wt_h)[i];

    // A fragments direct from global nei (already bf16, fragment-aligned reads)
    const int arow = row0 + wid * 16 + l15;
    s16x8 afrag[4];
    if (arow < Ee) {
        #pragma unroll
        for (int ks = 0; ks < 4; ++ks)
            afrag[ks] = *(const s16x8*)(nei + (size_t)arow * Hh + ks * 32 + l4 * 8);
    } else {
        #pragma unroll
        for (int ks = 0; ks < 4; ++ks)
            afrag[ks] = (s16x8){0, 0, 0, 0, 0, 0, 0, 0};
    }
    __syncthreads();   // W staged

    f32x4 acc[8];
    #pragma unroll
    for (int b = 0; b < 8; ++b) acc[b] = (f32x4){0.f, 0.f, 0.f, 0.f};
    #pragma unroll
    for (int ks = 0; ks < 4; ++ks)
        #pragma unroll
        for (int c = 0; c < 8; ++c) {
            s16x8 b = ((const s16x8*)u.W)[(ks * 8 + c) * 64 + lane];
            acc[c] = __builtin_amdgcn_mfma_f32_16x16x32_bf16(afrag[ks], b, acc[c], 0, 0, 0);
        }
    __syncthreads();   // all waves done reading W

    // epilogue in two 64-row halves through the union acc buffer
    #pragma unroll
    for (int h = 0; h < 2; ++h) {
        if ((wid >> 2) == h) {
            #pragma unroll
            for (int c = 0; c < 8; ++c)
                #pragma unroll
                for (int j = 0; j < 4; ++j)
                    u.acc[(wid & 3) * 16 + l4 * 4 + j][c * 16 + l15] = acc[c][j];
        }
        __syncthreads();
        for (int i = t; i < 64 * 16; i += 512) {
            int r = i >> 4, seg = i & 15;
            int g = row0 + h * 64 + r;
            if (g < Ee) {
                float4 a0 = *(const float4*)&u.acc[r][seg * 8];
                float4 a1 = *(const float4*)&u.acc[r][seg * 8 + 4];
                size_t o = (size_t)g * Hh + seg * 8;
                uint4 bv = *(const uint4*)&binput_bf[o];
                uint4 m;
                m.x = pack2(sigmoidf_(a0.x + bflo(bv.x)), sigmoidf_(a0.y + bfhi(bv.x)));
                m.y = pack2(sigmoidf_(a0.z + bflo(bv.y)), sigmoidf_(a0.w + bfhi(bv.y)));
                m.z = pack2(sigmoidf_(a1.x + bflo(bv.z)), sigmoidf_(a1.y + bfhi(bv.z)));
                m.w = pack2(sigmoidf_(a1.z + bflo(bv.w)), sigmoidf_(a1.w + bfhi(bv.w)));
                *(uint4*)&msg_out[o] = m;
            }
        }
        __syncthreads();
    }
}

// ---------------------------------------------------------------------------
// Kernel 3 (MFMA): hidden = bf16(sigmoid([feat|0pad|nei] @ W_o' + b_o)), K=192
// 64 rows / block, 4 waves. Fragment-major W_o.
// ---------------------------------------------------------------------------
union WoSmem {
    u16 Wo[48 * 512];       // 49152 B, fragment-major
    float acc[64][ACCW];    // 33792 B
};

__global__ __launch_bounds__(256, 2) void k_final(
    const u16* __restrict__ msg_in, const int* __restrict__ agraph,
    const float* __restrict__ features, const u16* __restrict__ wt_o,
    const float* __restrict__ b_o, u16* __restrict__ hidden)
{
    __shared__ WoSmem uw;
    __shared__ u16 sA[64 * KO];     // 25600 B
    __shared__ int sAG[64 * NBn];   // 2048 B
    __shared__ float sBias[Hh];     // 512 B
    const int t = threadIdx.x;
    const int row0 = blockIdx.x * 64;
    const int nvalid = min(64, Nn - row0);

    for (int i = t; i < 48 * 512 / 8; i += 256)
        ((uint4*)uw.Wo)[i] = ((const uint4*)wt_o)[i];
    {
        uint4 z = make_uint4(0, 0, 0, 0);
        for (int i = t; i < 64 * KO / 8; i += 256) ((uint4*)sA)[i] = z;
    }
    if (t < 128) {
        int r = row0 + (t >> 1);
        int4 v = make_int4(0, 0, 0, 0);
        if (r < Nn) v = ((const int4*)agraph)[r * 2 + (t & 1)];
        ((int4*)sAG)[t] = v;
    }
    if (t < Hh / 4) ((float4*)sBias)[t] = ((const float4*)b_o)[t];
    __syncthreads();

    for (int i = t; i < nvalid * FFn; i += 256) {
        int r = i / FFn, k = i - r * FFn;
        sA[r * KO + k] = f2bf(features[(size_t)row0 * FFn + i]);
    }
    {
        const int s = t & 15, rl = t >> 4;
        #pragma unroll 2
        for (int pass = 0; pass < 4; ++pass) {
            int r = pass * 16 + rl;
            int grow = row0 + r;
            float a[8] = {0.f, 0.f, 0.f, 0.f, 0.f, 0.f, 0.f, 0.f};
            if (grow < Nn) {
                #pragma unroll
                for (int j = 0; j < NBn; ++j) {
                    int idx = sAG[r * NBn + j];
                    uint4 v = *(const uint4*)(msg_in + (size_t)idx * Hh + s * 8);
                    add8(a, v);
                }
            }
            uint4 o;
            o.x = pack2(a[0], a[1]); o.y = pack2(a[2], a[3]);
            o.z = pack2(a[4], a[5]); o.w = pack2(a[6], a[7]);
            *(uint4*)&sA[r * KO + 64 + s * 8] = o;
        }
    }
    __syncthreads();

    const int lane = t & 63, wid = t >> 6, l15 = lane & 15, l4 = lane >> 4;
    f32x4 acc[8];
    #pragma unroll
    for (int b = 0; b < 8; ++b) acc[b] = (f32x4){0.f, 0.f, 0.f, 0.f};

    #pragma unroll
    for (int ks = 0; ks < 6; ++ks) {
        s16x8 a = *(const s16x8*)&sA[(wid * 16 + l15) * KO + ks * 32 + l4 * 8];
        #pragma unroll
        for (int c = 0; c < 8; ++c) {
            s16x8 b = ((const s16x8*)uw.Wo)[(ks * 8 + c) * 64 + lane];
            acc[c] = __builtin_amdgcn_mfma_f32_16x16x32_bf16(a, b, acc[c], 0, 0, 0);
        }
    }
    __syncthreads();

    #pragma unroll
    for (int c = 0; c < 8; ++c)
        #pragma unroll
        for (int j = 0; j < 4; ++j)
            uw.acc[wid * 16 + l4 * 4 + j][c * 16 + l15] = acc[c][j];
    __syncthreads();

    for (int i = t; i < 64 * 16; i += 256) {
        int row = i >> 4, seg = i & 15, grow = row0 + row;
        if (grow < Nn) {
            float4 a0 = *(const float4*)&uw.acc[row][seg * 8];
            float4 a1 = *(const float4*)&uw.acc[row][seg * 8 + 4];
            const float* bb = &sBias[seg * 8];
            uint4 m;
            m.x = pack2(sigmoidf_(a0.x + bb[0]), sigmoidf_(a0.y + bb[1]));
            m.y = pack2(sigmoidf_(a0.z + bb[2]), sigmoidf_(a0.w + bb[3]));
            m.z = pack2(sigmoidf_(a1.x + bb[4]), sigmoidf_(a1.y + bb[5]));
            m.w = pack2(sigmoidf_(a1.z + bb[6]), sigmoidf_(a1.w + bb[7]));
            *(uint4*)&hidden[(size_t)grow * Hh + seg * 8] = m;
        }
    }
}

// ---------------------------------------------------------------------------
// Kernel 4: segment mean over bf16 hidden. One block (128 threads) / molecule.
// ---------------------------------------------------------------------------
__global__ __launch_bounds__(128) void k_pool(
    const u16* __restrict__ hidden, const int* __restrict__ scope,
    float* __restrict__ out)
{
    const int b = blockIdx.x;
    const int t = threadIdx.x;
    const int start = scope[b * 2 + 0];
    const int len   = scope[b * 2 + 1];
    float acc = 0.f;
    for (int i = 0; i < len; ++i)
        acc += bf1(hidden[(size_t)(start + i) * Hh + t]);
    out[(size_t)b * Hh + t] = acc / (float)len;
}

// ---------------------------------------------------------------------------
extern "C" void kernel_launch(void* const* d_in, const int* in_sizes, int n_in,
                              void* d_out, int out_size, void* d_ws, size_t ws_size,
                              hipStream_t stream)
{
    const float* features = (const float*)d_in[0];
    const float* fedges   = (const float*)d_in[1];
    const int*   agraph   = (const int*)d_in[2];
    const int*   egraph   = (const int*)d_in[3];
    const int*   scope    = (const int*)d_in[4];
    const float* W_i      = (const float*)d_in[5];
    const float* W_h      = (const float*)d_in[6];
    const float* W_o      = (const float*)d_in[7];
    const float* b_o      = (const float*)d_in[8];
    float* out = (float*)d_out;

    // Workspace (all bf16 E*128 planes): nei | binput | msg0 | msg1 | wt_h
    // wt_i parks in msg1 (consumed by k_binput before iter0's gemm writes it);
    // wt_o parks in nei (dead after the last k_gemm).
    u16* nei       = (u16*)d_ws;
    u16* binput_bf = nei + (size_t)Ee * Hh;
    u16* msg0      = binput_bf + (size_t)Ee * Hh;
    u16* msg1      = msg0 + (size_t)Ee * Hh;
    u16* wt_h      = msg1 + (size_t)Ee * Hh;  // 16384 u16
    u16* wt_i      = msg1;                    // 8192 u16
    u16* wt_o      = nei;                     // 24576 u16

    k_prep1<<<(Hh * Hh + 16 * 512 + 255) / 256, 256, 0, stream>>>(W_h, W_i, wt_h, wt_i);

    const int eblocks = (Ee + 127) / 128;
    k_binput<<<eblocks, 512, 0, stream>>>(fedges, wt_i, binput_bf, msg0);

    const int gblocks = (Ee * NBn + 255) / 256;   // 8 lanes/row
    u16* src = msg0;
    u16* dst = msg1;
    for (int d = 0; d < ITERS; ++d) {
        k_gather<<<gblocks, 256, 0, stream>>>(src, egraph, nei);
        k_gemm<<<eblocks, 512, 0, stream>>>(nei, wt_h, binput_bf, dst);
        u16* tmp = src; src = dst; dst = tmp;
    }
    // final message in `src` (= msg1); nei now dead -> prep wt_o there.
    k_prep2<<<(48 * 512) / 256, 256, 0, stream>>>(W_o, wt_o);

    u16* hidden = dst;   // = msg0 region
    const int nblocks = (Nn + 63) / 64;
    k_final<<<nblocks, 256, 0, stream>>>(src, agraph, features, wt_o, b_o, hidden);

    k_pool<<<Bm, 128, 0, stream>>>(hidden, scope, out);
}